// Round 1
// baseline (1455.542 us; speedup 1.0000x reference)
//
#include <hip/hip_runtime.h>
#include <math.h>

// Problem constants (from reference)
#define NN 50000
#define NE 500000
#define HC 128      // HEADS*OUT_CH
#define TD 64       // TIME_DIM
#define MD 128      // MSG_DIM
#define ED 192      // EDGE_DIM
#define TILE_E 32   // edges per tile in edge kernel
#define EAS 34      // eaT row stride (words): 34 ≡ 2 mod 32 -> 2-way (free) banks, 8B-aligned b64 reads

// ---------------------------------------------------------------------------
// K1: node projections q,k,v,skip = x @ {Wq,Wk,Wv,Wskip} + bias
// 32 nodes per block, 256 threads: c = t&127 (output channel), mg = t>>7 (node half)
// x tile staged transposed in LDS; each thread accumulates 16 nodes x 4 matrices.
// ---------------------------------------------------------------------------
__global__ __launch_bounds__(256) void proj_kernel(
    const float* __restrict__ x,
    const float* __restrict__ Wq, const float* __restrict__ bq,
    const float* __restrict__ Wk, const float* __restrict__ bk,
    const float* __restrict__ Wv, const float* __restrict__ bv,
    const float* __restrict__ Ws, const float* __restrict__ bs,
    float* __restrict__ q, float* __restrict__ k, float* __restrict__ v,
    float* __restrict__ skip)
{
    __shared__ float xT[128 * 36];   // xT[j][m], stride 36 (16B-aligned float4 reads)
    const int t  = threadIdx.x;
    const int c  = t & 127;
    const int mg = t >> 7;           // 0..1
    const int n0 = blockIdx.x * 32;

    // stage x transposed: 32 nodes x 128 ch (float4 over channels)
    for (int idx = t; idx < 32 * 32; idx += 256) {
        int m  = idx >> 5;
        int c4 = idx & 31;
        int n  = n0 + m;
        float4 xv = (n < NN) ? ((const float4*)x)[(size_t)n * 32 + c4]
                             : make_float4(0.f, 0.f, 0.f, 0.f);
        xT[(4 * c4 + 0) * 36 + m] = xv.x;
        xT[(4 * c4 + 1) * 36 + m] = xv.y;
        xT[(4 * c4 + 2) * 36 + m] = xv.z;
        xT[(4 * c4 + 3) * 36 + m] = xv.w;
    }
    __syncthreads();

    float accq[16], acck[16], accv[16], accs[16];
#pragma unroll
    for (int m = 0; m < 16; m++) { accq[m] = 0.f; acck[m] = 0.f; accv[m] = 0.f; accs[m] = 0.f; }

    const int mbase = mg * 16;
    for (int j = 0; j < 128; j++) {
        float wq = Wq[j * HC + c];
        float wk = Wk[j * HC + c];
        float wv = Wv[j * HC + c];
        float ws = Ws[j * HC + c];
        const float* xr = &xT[j * 36 + mbase];
#pragma unroll
        for (int mi = 0; mi < 4; mi++) {
            float4 xv = *(const float4*)&xr[4 * mi];
            accq[4*mi+0] += xv.x * wq; accq[4*mi+1] += xv.y * wq; accq[4*mi+2] += xv.z * wq; accq[4*mi+3] += xv.w * wq;
            acck[4*mi+0] += xv.x * wk; acck[4*mi+1] += xv.y * wk; acck[4*mi+2] += xv.z * wk; acck[4*mi+3] += xv.w * wk;
            accv[4*mi+0] += xv.x * wv; accv[4*mi+1] += xv.y * wv; accv[4*mi+2] += xv.z * wv; accv[4*mi+3] += xv.w * wv;
            accs[4*mi+0] += xv.x * ws; accs[4*mi+1] += xv.y * ws; accs[4*mi+2] += xv.z * ws; accs[4*mi+3] += xv.w * ws;
        }
    }

    const float biasq = bq[c], biask = bk[c], biasv = bv[c], biass = bs[c];
#pragma unroll
    for (int m = 0; m < 16; m++) {
        int n = n0 + mbase + m;
        if (n < NN) {
            size_t o = (size_t)n * HC + c;
            q[o]    = accq[m] + biasq;
            k[o]    = acck[m] + biask;
            v[o]    = accv[m] + biasv;
            skip[o] = accs[m] + biass;
        }
    }
}

// ---------------------------------------------------------------------------
// K2: per-edge fused kernel (one head per blockIdx.y):
//   edge_attr = [cos(rel_t*tw+tb), msg]  ->  e = edge_attr @ We(half)
//   a = exp( q[dst]·(k[src]+e) / 8 )     (no max-subtraction: mathematically identical)
//   atomic: nsum[dst,h] += a ;  out[dst, hb+c] += (v[src,hb+c]+e_c)*a
// 256 threads = 16 channel-groups(4ch) x 16 edge-groups(2 edges). We-half in LDS.
// ---------------------------------------------------------------------------
__global__ __launch_bounds__(256) void edge_kernel(
    const int*   __restrict__ ei,       // [2, E]
    const float* __restrict__ tarr,     // [E]
    const float* __restrict__ lastup,   // [N]
    const float* __restrict__ msg,      // [E, 128]
    const float* __restrict__ time_w,   // [64]
    const float* __restrict__ time_b,   // [64]
    const float* __restrict__ We,       // [192, 128]
    const float* __restrict__ q,
    const float* __restrict__ k,
    const float* __restrict__ v,
    float* __restrict__ out_un,         // [N, 128]  (d_out, pre-zeroed)
    float* __restrict__ nsum)           // [N, 2]    (pre-zeroed)
{
    const int h  = blockIdx.y;
    const int hb = h * 64;

    __shared__ float Wh[ED * 64];       // 48 KB: We[:, hb:hb+64]
    __shared__ float eaT[ED * EAS];     // 26.1 KB: edge_attr transposed [192][TILE_E]
    __shared__ int   srcs[TILE_E], dsts[TILE_E];
    __shared__ float relt[TILE_E];

    const int t = threadIdx.x;

    // stage We half (float4)
    for (int idx = t; idx < ED * 16; idx += 256) {
        int j  = idx >> 4;
        int c4 = idx & 15;
        float4 w = ((const float4*)We)[(size_t)j * 32 + h * 16 + c4];
        *(float4*)&Wh[j * 64 + 4 * c4] = w;
    }

    const int cg = t & 15;   // channel group: channels hb + 4*cg .. +3
    const int eg = t >> 4;   // edge group: edges 2*eg, 2*eg+1
    const int ntiles = NE / TILE_E;   // 15625 exactly

    for (int tile = blockIdx.x; tile < ntiles; tile += gridDim.x) {
        const int e0 = tile * TILE_E;
        __syncthreads();   // protect LDS from previous tile readers (also fences We stage)

        if (t < TILE_E) {
            int s = ei[e0 + t];
            int d = ei[NE + e0 + t];
            srcs[t] = s;
            dsts[t] = d;
            relt[t] = tarr[e0 + t] - lastup[s];
        }
        __syncthreads();

        // time encoding rows 0..63
        for (int idx = t; idx < TILE_E * TD; idx += 256) {
            int c = idx & 63;
            int e = idx >> 6;
            eaT[c * EAS + e] = __cosf(relt[e] * time_w[c] + time_b[c]);
        }
        // msg rows 64..191 (coalesced float4 global reads, transposed scatter to LDS)
        for (int idx = t; idx < TILE_E * 32; idx += 256) {
            int e  = idx >> 5;
            int c4 = idx & 31;
            float4 mv = ((const float4*)msg)[(size_t)(e0 + e) * 32 + c4];
            eaT[(TD + 4 * c4 + 0) * EAS + e] = mv.x;
            eaT[(TD + 4 * c4 + 1) * EAS + e] = mv.y;
            eaT[(TD + 4 * c4 + 2) * EAS + e] = mv.z;
            eaT[(TD + 4 * c4 + 3) * EAS + e] = mv.w;
        }
        __syncthreads();

        // e = edge_attr @ We(half): 4 channels x 2 edges per thread
        float acc[2][4];
#pragma unroll
        for (int i = 0; i < 4; i++) { acc[0][i] = 0.f; acc[1][i] = 0.f; }

        const float* WhP = &Wh[4 * cg];
        const float* eaP = &eaT[2 * eg];
#pragma unroll 4
        for (int j = 0; j < ED; j++) {
            float4 w = *(const float4*)&WhP[j * 64];
            float2 a = *(const float2*)&eaP[j * EAS];
            acc[0][0] += a.x * w.x; acc[0][1] += a.x * w.y; acc[0][2] += a.x * w.z; acc[0][3] += a.x * w.w;
            acc[1][0] += a.y * w.x; acc[1][1] += a.y * w.y; acc[1][2] += a.y * w.z; acc[1][3] += a.y * w.w;
        }

        // attention + scatter for the 2 local edges
#pragma unroll
        for (int le = 0; le < 2; le++) {
            int e = 2 * eg + le;
            int s = srcs[e];
            int d = dsts[e];
            size_t qo = (size_t)d * HC + hb + 4 * cg;
            size_t ko = (size_t)s * HC + hb + 4 * cg;
            float4 qv = *(const float4*)&q[qo];
            float4 kv = *(const float4*)&k[ko];
            float p = qv.x * (kv.x + acc[le][0]) + qv.y * (kv.y + acc[le][1])
                    + qv.z * (kv.z + acc[le][2]) + qv.w * (kv.w + acc[le][3]);
            // butterfly sum over the 16 contiguous lanes of this edge group
            p += __shfl_xor(p, 1);
            p += __shfl_xor(p, 2);
            p += __shfl_xor(p, 4);
            p += __shfl_xor(p, 8);
            float alpha = __expf(p * 0.125f);   // 1/sqrt(64)
            if (cg == 0) atomicAdd(&nsum[(size_t)d * 2 + h], alpha);
            float4 vv = *(const float4*)&v[ko];
            float* op = &out_un[qo];
            atomicAdd(op + 0, (vv.x + acc[le][0]) * alpha);
            atomicAdd(op + 1, (vv.y + acc[le][1]) * alpha);
            atomicAdd(op + 2, (vv.z + acc[le][2]) * alpha);
            atomicAdd(op + 3, (vv.w + acc[le][3]) * alpha);
        }
    }
}

// ---------------------------------------------------------------------------
// K3: out = out_un / (nsum + 1e-16) + skip   (float4 per thread)
// ---------------------------------------------------------------------------
__global__ __launch_bounds__(256) void finalize_kernel(
    float* __restrict__ out, const float* __restrict__ nsum,
    const float* __restrict__ skip)
{
    int i = blockIdx.x * blockDim.x + threadIdx.x;   // over N*32 float4s
    if (i >= NN * 32) return;
    int n  = i >> 5;
    int c4 = i & 31;
    int h  = c4 >> 4;
    float z = nsum[(size_t)n * 2 + h] + 1e-16f;
    float inv = 1.0f / z;
    float4 o = ((float4*)out)[i];
    float4 s = ((const float4*)skip)[i];
    o.x = o.x * inv + s.x;
    o.y = o.y * inv + s.y;
    o.z = o.z * inv + s.z;
    o.w = o.w * inv + s.w;
    ((float4*)out)[i] = o;
}

// ---------------------------------------------------------------------------
extern "C" void kernel_launch(void* const* d_in, const int* in_sizes, int n_in,
                              void* d_out, int out_size, void* d_ws, size_t ws_size,
                              hipStream_t stream) {
    const float* x      = (const float*)d_in[0];
    const float* lastup = (const float*)d_in[1];
    const float* tarr   = (const float*)d_in[2];
    const float* msg    = (const float*)d_in[3];
    const float* time_w = (const float*)d_in[4];
    const float* time_b = (const float*)d_in[5];
    const float* Wq     = (const float*)d_in[6];
    const float* bq     = (const float*)d_in[7];
    const float* Wk     = (const float*)d_in[8];
    const float* bk     = (const float*)d_in[9];
    const float* Wv     = (const float*)d_in[10];
    const float* bv     = (const float*)d_in[11];
    const float* We     = (const float*)d_in[12];
    const float* Wskip  = (const float*)d_in[13];
    const float* bskip  = (const float*)d_in[14];
    const int*   ei     = (const int*)d_in[15];

    // ws layout (floats): q | k | v | skip | nsum   (total ~102.8 MB)
    float* ws   = (float*)d_ws;
    float* q    = ws;
    float* k    = q    + (size_t)NN * HC;
    float* v    = k    + (size_t)NN * HC;
    float* skip = v    + (size_t)NN * HC;
    float* nsum = skip + (size_t)NN * HC;
    float* out  = (float*)d_out;

    hipMemsetAsync(out,  0, (size_t)NN * HC * sizeof(float), stream);
    hipMemsetAsync(nsum, 0, (size_t)NN * 2  * sizeof(float), stream);

    proj_kernel<<<dim3((NN + 31) / 32), 256, 0, stream>>>(
        x, Wq, bq, Wk, bk, Wv, bv, Wskip, bskip, q, k, v, skip);

    edge_kernel<<<dim3(256, 2), 256, 0, stream>>>(
        ei, tarr, lastup, msg, time_w, time_b, We, q, k, v, out, nsum);

    finalize_kernel<<<dim3((NN * 32 + 255) / 256), 256, 0, stream>>>(out, nsum, skip);
}

// Round 2
// 822.618 us; speedup vs baseline: 1.7694x; 1.7694x over previous
//
#include <hip/hip_runtime.h>
#include <math.h>

// Problem constants
#define NN 50000
#define NE 500000
#define HC 128      // HEADS*OUT_CH
#define TD 64       // TIME_DIM
#define MD 128      // MSG_DIM
#define ED 192      // EDGE_DIM
#define TILE_E 32   // edges per block in edge kernel
#define EAS 200     // ea row stride in bf16 (192+8): 400 B = 25*16B (aligned), 100 words = 4 mod 32 banks

typedef __attribute__((ext_vector_type(8))) short bf16x8;
typedef __attribute__((ext_vector_type(4))) float f32x4;

__device__ __forceinline__ short f2bf(float f) {
    union { float f; unsigned u; } a; a.f = f;
    unsigned r = a.u + 0x7fff + ((a.u >> 16) & 1);   // round-to-nearest-even
    return (short)(r >> 16);
}

// ---------------------------------------------------------------------------
// prep: WeT_bf16[n][k] = bf16(We[k][n])   (128 x 192, B-operand friendly)
// ---------------------------------------------------------------------------
__global__ __launch_bounds__(256) void prep_weT(const float* __restrict__ We,
                                                short* __restrict__ WeT) {
    int i = blockIdx.x * 256 + threadIdx.x;
    if (i >= HC * ED) return;
    int n = i / ED, kk = i % ED;
    WeT[i] = f2bf(We[(size_t)kk * HC + n]);
}

// ---------------------------------------------------------------------------
// K1: node projections q,k,v,skip = x @ {Wq,Wk,Wv,Wskip} + bias (unchanged)
// ---------------------------------------------------------------------------
__global__ __launch_bounds__(256) void proj_kernel(
    const float* __restrict__ x,
    const float* __restrict__ Wq, const float* __restrict__ bq,
    const float* __restrict__ Wk, const float* __restrict__ bk,
    const float* __restrict__ Wv, const float* __restrict__ bv,
    const float* __restrict__ Ws, const float* __restrict__ bs,
    float* __restrict__ q, float* __restrict__ k, float* __restrict__ v,
    float* __restrict__ skip)
{
    __shared__ float xT[128 * 36];
    const int t  = threadIdx.x;
    const int c  = t & 127;
    const int mg = t >> 7;
    const int n0 = blockIdx.x * 32;

    for (int idx = t; idx < 32 * 32; idx += 256) {
        int m  = idx >> 5;
        int c4 = idx & 31;
        int n  = n0 + m;
        float4 xv = (n < NN) ? ((const float4*)x)[(size_t)n * 32 + c4]
                             : make_float4(0.f, 0.f, 0.f, 0.f);
        xT[(4 * c4 + 0) * 36 + m] = xv.x;
        xT[(4 * c4 + 1) * 36 + m] = xv.y;
        xT[(4 * c4 + 2) * 36 + m] = xv.z;
        xT[(4 * c4 + 3) * 36 + m] = xv.w;
    }
    __syncthreads();

    float accq[16], acck[16], accv[16], accs[16];
#pragma unroll
    for (int m = 0; m < 16; m++) { accq[m] = 0.f; acck[m] = 0.f; accv[m] = 0.f; accs[m] = 0.f; }

    const int mbase = mg * 16;
    for (int j = 0; j < 128; j++) {
        float wq = Wq[j * HC + c];
        float wk = Wk[j * HC + c];
        float wv = Wv[j * HC + c];
        float ws = Ws[j * HC + c];
        const float* xr = &xT[j * 36 + mbase];
#pragma unroll
        for (int mi = 0; mi < 4; mi++) {
            float4 xv = *(const float4*)&xr[4 * mi];
            accq[4*mi+0] += xv.x * wq; accq[4*mi+1] += xv.y * wq; accq[4*mi+2] += xv.z * wq; accq[4*mi+3] += xv.w * wq;
            acck[4*mi+0] += xv.x * wk; acck[4*mi+1] += xv.y * wk; acck[4*mi+2] += xv.z * wk; acck[4*mi+3] += xv.w * wk;
            accv[4*mi+0] += xv.x * wv; accv[4*mi+1] += xv.y * wv; accv[4*mi+2] += xv.z * wv; accv[4*mi+3] += xv.w * wv;
            accs[4*mi+0] += xv.x * ws; accs[4*mi+1] += xv.y * ws; accs[4*mi+2] += xv.z * ws; accs[4*mi+3] += xv.w * ws;
        }
    }

    const float biasq = bq[c], biask = bk[c], biasv = bv[c], biass = bs[c];
#pragma unroll
    for (int m = 0; m < 16; m++) {
        int n = n0 + mbase + m;
        if (n < NN) {
            size_t o = (size_t)n * HC + c;
            q[o]    = accq[m] + biasq;
            k[o]    = acck[m] + biask;
            v[o]    = accv[m] + biass * 0.f + accv[m] * 0.f + acck[m] * 0.f + accv[m] * 0.f; // placeholder removed below
        }
    }
    // NOTE: rewritten store loop (no placeholder)
#pragma unroll
    for (int m = 0; m < 16; m++) {
        int n = n0 + mbase + m;
        if (n < NN) {
            size_t o = (size_t)n * HC + c;
            q[o]    = accq[m] + biasq;
            k[o]    = acck[m] + biask;
            v[o]    = accv[m] + biasv;
            skip[o] = accs[m] + biass;
        }
    }
}

// ---------------------------------------------------------------------------
// K2: MFMA edge kernel. One 32-edge tile per block; 4 waves:
//   wave w: head h=w>>1, edges half=(w&1)*16 .. +15.
// edge_attr tile staged in LDS as bf16 [32][EAS]; e = ea @ We (bf16 MFMA,
// fp32 acc, 16x16x32, K=192 in 6 steps x 4 N-tiles of 16 ch).
// Then alpha = exp(q[dst]·(k[src]+e)/8) directly in C-layout
// (channel = lane&15 (+16*nt), edge = (lane>>4)*4+reg), butterfly over the
// 16 channel-lanes, atomic scatter of (v[src]+e)*alpha and nsum.
// ---------------------------------------------------------------------------
__global__ __launch_bounds__(256) void edge_kernel(
    const int*   __restrict__ ei,
    const float* __restrict__ tarr,
    const float* __restrict__ lastup,
    const float* __restrict__ msg,
    const float* __restrict__ time_w,
    const float* __restrict__ time_b,
    const short* __restrict__ WeT,      // [128][192] bf16
    const float* __restrict__ q,
    const float* __restrict__ k,
    const float* __restrict__ v,
    float* __restrict__ out_un,         // [N,128] pre-zeroed
    float* __restrict__ nsum)           // [N,2]  pre-zeroed
{
    __shared__ short ea[TILE_E * EAS];  // 12.5 KB bf16 edge_attr tile
    __shared__ int   srcs[TILE_E], dsts[TILE_E];
    __shared__ float relt[TILE_E];

    const int t  = threadIdx.x;
    const int e0 = blockIdx.x * TILE_E;

    if (t < TILE_E) {
        int s = ei[e0 + t];
        int d = ei[NE + e0 + t];
        srcs[t] = s; dsts[t] = d;
        relt[t] = tarr[e0 + t] - lastup[s];
    }
    __syncthreads();

    // time encoding -> ea[:, 0:64) as bf16 (cos computed once, shared by both heads)
    for (int idx = t; idx < TILE_E * 32; idx += 256) {
        int e  = idx >> 5;
        int c2 = idx & 31;
        float r  = relt[e];
        float c0 = __cosf(r * time_w[2 * c2]     + time_b[2 * c2]);
        float c1 = __cosf(r * time_w[2 * c2 + 1] + time_b[2 * c2 + 1]);
        short2 p; p.x = f2bf(c0); p.y = f2bf(c1);
        *(short2*)&ea[e * EAS + 2 * c2] = p;
    }
    // msg -> ea[:, 64:192) as bf16 (coalesced float4 reads)
    for (int idx = t; idx < TILE_E * 32; idx += 256) {
        int e  = idx >> 5;
        int c4 = idx & 31;
        float4 m = ((const float4*)msg)[(size_t)(e0 + e) * 32 + c4];
        short4 p; p.x = f2bf(m.x); p.y = f2bf(m.y); p.z = f2bf(m.z); p.w = f2bf(m.w);
        *(short4*)&ea[e * EAS + TD + 4 * c4] = p;
    }
    __syncthreads();

    const int w    = t >> 6;      // wave 0..3
    const int h    = w >> 1;      // head
    const int half = w & 1;       // edge half (0: edges 0-15, 1: 16-31)
    const int lane = t & 63;
    const int qd   = lane >> 4;   // k-block for A/B frags; edge-quad for C
    const int c    = lane & 15;   // A row (edge) for frag load; channel for C
    const int hb   = h * 64;

    f32x4 acc[4];
#pragma unroll
    for (int nt = 0; nt < 4; nt++) acc[nt] = (f32x4){0.f, 0.f, 0.f, 0.f};

    // A: row (edge) = lane&15, k = (lane>>4)*8 + j  -> 16B contiguous bf16
    const short* aP = &ea[(half * 16 + c) * EAS + qd * 8];
    // B: col (channel) = lane&15, k = (lane>>4)*8 + j -> WeT row-contiguous
    const short* bP = &WeT[(size_t)(hb + c) * ED + qd * 8];

#pragma unroll
    for (int kb = 0; kb < 6; kb++) {
        bf16x8 af = *(const bf16x8*)(aP + kb * 32);
#pragma unroll
        for (int nt = 0; nt < 4; nt++) {
            bf16x8 bfv = *(const bf16x8*)(bP + (size_t)nt * 16 * ED + kb * 32);
            acc[nt] = __builtin_amdgcn_mfma_f32_16x16x32_bf16(af, bfv, acc[nt], 0, 0, 0);
        }
    }

    // attention + scatter: C layout: acc[nt][r] = e[edge qd*4+r][ch nt*16+c]
#pragma unroll
    for (int r = 0; r < 4; r++) {
        int m  = qd * 4 + r;
        int le = half * 16 + m;
        int s  = srcs[le];
        int d  = dsts[le];
        size_t qbase = (size_t)d * HC + hb + c;
        size_t kbase = (size_t)s * HC + hb + c;
        float p = 0.f;
#pragma unroll
        for (int nt = 0; nt < 4; nt++)
            p += q[qbase + nt * 16] * (k[kbase + nt * 16] + acc[nt][r]);
        p += __shfl_xor(p, 1);
        p += __shfl_xor(p, 2);
        p += __shfl_xor(p, 4);
        p += __shfl_xor(p, 8);
        float alpha = __expf(p * 0.125f);   // 1/sqrt(64)
        if (c == 0) atomicAdd(&nsum[(size_t)d * 2 + h], alpha);
        float* op = &out_un[qbase];
#pragma unroll
        for (int nt = 0; nt < 4; nt++)
            atomicAdd(op + nt * 16, (v[kbase + nt * 16] + acc[nt][r]) * alpha);
    }
}

// ---------------------------------------------------------------------------
// K3: out = out_un / (nsum + 1e-16) + skip
// ---------------------------------------------------------------------------
__global__ __launch_bounds__(256) void finalize_kernel(
    float* __restrict__ out, const float* __restrict__ nsum,
    const float* __restrict__ skip)
{
    int i = blockIdx.x * blockDim.x + threadIdx.x;
    if (i >= NN * 32) return;
    int n  = i >> 5;
    int c4 = i & 31;
    int h  = c4 >> 4;
    float z = nsum[(size_t)n * 2 + h] + 1e-16f;
    float inv = 1.0f / z;
    float4 o = ((float4*)out)[i];
    float4 s = ((const float4*)skip)[i];
    o.x = o.x * inv + s.x;
    o.y = o.y * inv + s.y;
    o.z = o.z * inv + s.z;
    o.w = o.w * inv + s.w;
    ((float4*)out)[i] = o;
}

// ---------------------------------------------------------------------------
extern "C" void kernel_launch(void* const* d_in, const int* in_sizes, int n_in,
                              void* d_out, int out_size, void* d_ws, size_t ws_size,
                              hipStream_t stream) {
    const float* x      = (const float*)d_in[0];
    const float* lastup = (const float*)d_in[1];
    const float* tarr   = (const float*)d_in[2];
    const float* msg    = (const float*)d_in[3];
    const float* time_w = (const float*)d_in[4];
    const float* time_b = (const float*)d_in[5];
    const float* Wq     = (const float*)d_in[6];
    const float* bq     = (const float*)d_in[7];
    const float* Wk     = (const float*)d_in[8];
    const float* bk     = (const float*)d_in[9];
    const float* Wv     = (const float*)d_in[10];
    const float* bv     = (const float*)d_in[11];
    const float* We     = (const float*)d_in[12];
    const float* Wskip  = (const float*)d_in[13];
    const float* bskip  = (const float*)d_in[14];
    const int*   ei     = (const int*)d_in[15];

    // ws layout (floats): q | k | v | skip | nsum | WeT(bf16)
    float* ws   = (float*)d_ws;
    float* q    = ws;
    float* k    = q    + (size_t)NN * HC;
    float* v    = k    + (size_t)NN * HC;
    float* skip = v    + (size_t)NN * HC;
    float* nsum = skip + (size_t)NN * HC;
    short* WeT  = (short*)(nsum + (size_t)NN * 2);
    float* out  = (float*)d_out;

    hipMemsetAsync(out,  0, (size_t)NN * HC * sizeof(float), stream);
    hipMemsetAsync(nsum, 0, (size_t)NN * 2  * sizeof(float), stream);

    prep_weT<<<dim3((HC * ED + 255) / 256), 256, 0, stream>>>(We, WeT);

    proj_kernel<<<dim3((NN + 31) / 32), 256, 0, stream>>>(
        x, Wq, bq, Wk, bk, Wv, bv, Wskip, bskip, q, k, v, skip);

    edge_kernel<<<dim3(NE / TILE_E), 256, 0, stream>>>(
        ei, tarr, lastup, msg, time_w, time_b, WeT, q, k, v, out, nsum);

    finalize_kernel<<<dim3((NN * 32 + 255) / 256), 256, 0, stream>>>(out, nsum, skip);
}

// Round 3
// 774.184 us; speedup vs baseline: 1.8801x; 1.0626x over previous
//
#include <hip/hip_runtime.h>
#include <math.h>

// Problem constants
#define NN 50000
#define NE 500000
#define HC 128      // HEADS*OUT_CH
#define TD 64       // TIME_DIM
#define ED 192      // EDGE_DIM
#define TILE_E 32   // edges per block in edge kernel
#define EAS 200     // ea row stride bf16: 400B (16B-aligned), 100 words = 4 mod 32 banks (2-way, free)
#define PXS 136     // proj x-tile stride bf16: 272B (16B-aligned), 68 words = 4 mod 32 banks

typedef __attribute__((ext_vector_type(8))) short bf16x8;
typedef __attribute__((ext_vector_type(4))) float f32x4;
typedef __attribute__((ext_vector_type(2))) short v2s;

__device__ __forceinline__ short f2bf(float f) {
    union { float f; unsigned u; } a; a.f = f;
    unsigned r = a.u + 0x7fff + ((a.u >> 16) & 1);   // RNE
    return (short)(r >> 16);
}
__device__ __forceinline__ float bf2f(short s) {
    union { unsigned u; float f; } a; a.u = ((unsigned)(unsigned short)s) << 16;
    return a.f;
}

// pk bf16 atomic add (2 channels per L2 atomic op)
__device__ __forceinline__ void atomic_pk_add_bf16(short* addr, float lo, float hi) {
#if __has_builtin(__builtin_amdgcn_global_atomic_fadd_v2bf16)
    v2s val; val[0] = f2bf(lo); val[1] = f2bf(hi);
    __builtin_amdgcn_global_atomic_fadd_v2bf16(
        (__attribute__((address_space(1))) v2s*)addr, val);
#else
    // fallback: CAS loop on packed pair
    unsigned* p = (unsigned*)addr;
    unsigned old = *p, assumed;
    do {
        assumed = old;
        float l = bf2f((short)(assumed & 0xffff)) + lo;
        float h = bf2f((short)(assumed >> 16)) + hi;
        unsigned nv = ((unsigned)(unsigned short)f2bf(h) << 16) | (unsigned short)f2bf(l);
        old = atomicCAS(p, assumed, nv);
    } while (old != assumed);
#endif
}

// ---------------------------------------------------------------------------
// prep: x -> bf16
// ---------------------------------------------------------------------------
__global__ __launch_bounds__(256) void prep_xb(const float* __restrict__ x,
                                               short* __restrict__ xb) {
    int i = blockIdx.x * 256 + threadIdx.x;   // over NN*32 float4s
    if (i >= NN * 32) return;
    float4 v = ((const float4*)x)[i];
    short4 o; o.x = f2bf(v.x); o.y = f2bf(v.y); o.z = f2bf(v.z); o.w = f2bf(v.w);
    ((short4*)xb)[i] = o;
}

// ---------------------------------------------------------------------------
// prep: WeT[n][k] = bf16(We[k][n])  (128x192)  and
//       WT[m][n][k] = bf16(W_m[k][n]) for m in {q,k,v,skip} (4 x 128 x 128)
// ---------------------------------------------------------------------------
__global__ __launch_bounds__(256) void prep_weights(
    const float* __restrict__ We,
    const float* __restrict__ Wq, const float* __restrict__ Wk,
    const float* __restrict__ Wv, const float* __restrict__ Ws,
    short* __restrict__ WeT, short* __restrict__ WT) {
    int i = blockIdx.x * 256 + threadIdx.x;
    if (i < HC * ED) {
        int n = i / ED, kk = i % ED;
        WeT[i] = f2bf(We[(size_t)kk * HC + n]);
    }
    int j = i - HC * ED;
    if (j >= 0 && j < 4 * 128 * 128) {
        int m = j >> 14, r = j & 16383, n = r >> 7, kk = r & 127;
        const float* W = (m == 0) ? Wq : (m == 1) ? Wk : (m == 2) ? Wv : Ws;
        WT[j] = f2bf(W[kk * 128 + n]);
    }
}

// ---------------------------------------------------------------------------
// K1: MFMA projections. Block = 32 nodes, 4 waves; wave w computes output
// matrix w (q,k,v,skip) for all 32 nodes x 128 out-ch. 16x16x32 bf16 MFMA:
// 2 m-tiles x 8 n-tiles x 4 k-blocks = 64 MFMA/wave.
// ---------------------------------------------------------------------------
__global__ __launch_bounds__(256) void proj_mfma(
    const short* __restrict__ xb,     // [NN][128] bf16
    const short* __restrict__ WT,     // [4][128][128] bf16 (n-major)
    const float* __restrict__ bq, const float* __restrict__ bk,
    const float* __restrict__ bv, const float* __restrict__ bs,
    float* __restrict__ q, float* __restrict__ k, float* __restrict__ v,
    float* __restrict__ skip)
{
    __shared__ short xs[32 * PXS];   // 8.7 KB
    const int t  = threadIdx.x;
    const int n0 = blockIdx.x * 32;

    for (int idx = t; idx < 32 * 16; idx += 256) {
        int m  = idx >> 4;
        int c8 = idx & 15;
        int n  = n0 + m;
        bf16x8 val = {0, 0, 0, 0, 0, 0, 0, 0};
        if (n < NN) val = ((const bf16x8*)xb)[(size_t)n * 16 + c8];
        *(bf16x8*)&xs[m * PXS + c8 * 8] = val;
    }
    __syncthreads();

    const int w    = t >> 6;
    const int lane = t & 63;
    const int c    = lane & 15;
    const int qd   = lane >> 4;
    const short* WTm = WT + (size_t)w * 16384;

    f32x4 acc[2][8];
#pragma unroll
    for (int mt = 0; mt < 2; mt++)
#pragma unroll
        for (int nt = 0; nt < 8; nt++) acc[mt][nt] = (f32x4){0.f, 0.f, 0.f, 0.f};

#pragma unroll
    for (int kb = 0; kb < 4; kb++) {
        bf16x8 a0 = *(const bf16x8*)&xs[c * PXS + qd * 8 + kb * 32];
        bf16x8 a1 = *(const bf16x8*)&xs[(16 + c) * PXS + qd * 8 + kb * 32];
#pragma unroll
        for (int nt = 0; nt < 8; nt++) {
            bf16x8 b = *(const bf16x8*)&WTm[(size_t)(nt * 16 + c) * 128 + qd * 8 + kb * 32];
            acc[0][nt] = __builtin_amdgcn_mfma_f32_16x16x32_bf16(a0, b, acc[0][nt], 0, 0, 0);
            acc[1][nt] = __builtin_amdgcn_mfma_f32_16x16x32_bf16(a1, b, acc[1][nt], 0, 0, 0);
        }
    }

    float* dst = (w == 0) ? q : (w == 1) ? k : (w == 2) ? v : skip;
    const float* bias = (w == 0) ? bq : (w == 1) ? bk : (w == 2) ? bv : bs;
    float bvals[8];
#pragma unroll
    for (int nt = 0; nt < 8; nt++) bvals[nt] = bias[nt * 16 + c];

#pragma unroll
    for (int mt = 0; mt < 2; mt++) {
#pragma unroll
        for (int r = 0; r < 4; r++) {
            int n = n0 + mt * 16 + qd * 4 + r;
            if (n < NN) {
                float* dp = dst + (size_t)n * HC + c;
#pragma unroll
                for (int nt = 0; nt < 8; nt++)
                    dp[nt * 16] = acc[mt][nt][r] + bvals[nt];
            }
        }
    }
}

// ---------------------------------------------------------------------------
// K2: MFMA edge kernel. One 32-edge tile per block; wave w: head h=w>>1,
// edges half=(w&1)*16..+15. q/k/v gathers prefetched into registers right
// after the index barrier (latency overlaps ea staging + MFMA). Output
// accumulated as bf16 pairs via global_atomic_pk_add_bf16.
// ---------------------------------------------------------------------------
__global__ __launch_bounds__(256) void edge_kernel(
    const int*   __restrict__ ei,
    const float* __restrict__ tarr,
    const float* __restrict__ lastup,
    const float* __restrict__ msg,
    const float* __restrict__ time_w,
    const float* __restrict__ time_b,
    const short* __restrict__ WeT,      // [128][192] bf16
    const float* __restrict__ q,
    const float* __restrict__ k,
    const float* __restrict__ v,
    short* __restrict__ out_bf,         // [N][128] bf16, pre-zeroed
    float* __restrict__ nsum)           // [N][2] fp32, pre-zeroed
{
    __shared__ short ea[TILE_E * EAS];  // 12.5 KB
    __shared__ int   srcs[TILE_E], dsts[TILE_E];
    __shared__ float relt[TILE_E];

    const int t  = threadIdx.x;
    const int e0 = blockIdx.x * TILE_E;

    if (t < TILE_E) {
        int s = ei[e0 + t];
        int d = ei[NE + e0 + t];
        srcs[t] = s; dsts[t] = d;
        relt[t] = tarr[e0 + t] - lastup[s];
    }
    __syncthreads();

    const int w    = t >> 6;
    const int h    = w >> 1;
    const int half = w & 1;
    const int lane = t & 63;
    const int qd   = lane >> 4;
    const int c    = lane & 15;
    const int hb   = h * 64;

    // --- prefetch q[dst], k[src], v[src] for this wave's 4 edge-quads ---
    int dArr[4];
    float qv[4][4], kv[4][4], vv[4][4];
#pragma unroll
    for (int r = 0; r < 4; r++) {
        int le = half * 16 + qd * 4 + r;
        int s  = srcs[le];
        int d  = dsts[le];
        dArr[r] = d;
        const float* qp = q + (size_t)d * HC + hb + c;
        const float* kp = k + (size_t)s * HC + hb + c;
        const float* vp = v + (size_t)s * HC + hb + c;
#pragma unroll
        for (int nt = 0; nt < 4; nt++) {
            qv[r][nt] = qp[nt * 16];
            kv[r][nt] = kp[nt * 16];
            vv[r][nt] = vp[nt * 16];
        }
    }

    // --- stage edge_attr tile (bf16) ---
    for (int idx = t; idx < TILE_E * 32; idx += 256) {
        int e  = idx >> 5;
        int c2 = idx & 31;
        float r  = relt[e];
        float c0 = __cosf(r * time_w[2 * c2]     + time_b[2 * c2]);
        float c1 = __cosf(r * time_w[2 * c2 + 1] + time_b[2 * c2 + 1]);
        short2 p; p.x = f2bf(c0); p.y = f2bf(c1);
        *(short2*)&ea[e * EAS + 2 * c2] = p;
    }
    for (int idx = t; idx < TILE_E * 32; idx += 256) {
        int e  = idx >> 5;
        int c4 = idx & 31;
        float4 m = ((const float4*)msg)[(size_t)(e0 + e) * 32 + c4];
        short4 p; p.x = f2bf(m.x); p.y = f2bf(m.y); p.z = f2bf(m.z); p.w = f2bf(m.w);
        *(short4*)&ea[e * EAS + TD + 4 * c4] = p;
    }
    __syncthreads();

    // --- e = edge_attr @ We(half) via MFMA ---
    f32x4 acc[4];
#pragma unroll
    for (int nt = 0; nt < 4; nt++) acc[nt] = (f32x4){0.f, 0.f, 0.f, 0.f};

    const short* aP = &ea[(half * 16 + c) * EAS + qd * 8];
    const short* bP = &WeT[(size_t)(hb + c) * ED + qd * 8];

#pragma unroll
    for (int kb = 0; kb < 6; kb++) {
        bf16x8 af = *(const bf16x8*)(aP + kb * 32);
#pragma unroll
        for (int nt = 0; nt < 4; nt++) {
            bf16x8 bfv = *(const bf16x8*)(bP + (size_t)nt * 16 * ED + kb * 32);
            acc[nt] = __builtin_amdgcn_mfma_f32_16x16x32_bf16(af, bfv, acc[nt], 0, 0, 0);
        }
    }

    // --- attention + pk-bf16 scatter ---
#pragma unroll
    for (int r = 0; r < 4; r++) {
        int d = dArr[r];
        float p = 0.f;
#pragma unroll
        for (int nt = 0; nt < 4; nt++)
            p += qv[r][nt] * (kv[r][nt] + acc[nt][r]);
        p += __shfl_xor(p, 1);
        p += __shfl_xor(p, 2);
        p += __shfl_xor(p, 4);
        p += __shfl_xor(p, 8);
        float alpha = __expf(p * 0.125f);   // 1/sqrt(64)
        if (c == 0) atomicAdd(&nsum[(size_t)d * 2 + h], alpha);
        short* op = out_bf + (size_t)d * HC + hb + c;
#pragma unroll
        for (int nt = 0; nt < 4; nt++) {
            float val = (vv[r][nt] + acc[nt][r]) * alpha;
            float partner = __shfl_xor(val, 1);
            if ((lane & 1) == 0)
                atomic_pk_add_bf16(op + nt * 16, val, partner);
        }
    }
}

// ---------------------------------------------------------------------------
// K3: out = bf16_acc / (nsum + 1e-16) + skip
// ---------------------------------------------------------------------------
__global__ __launch_bounds__(256) void finalize_kernel(
    float* __restrict__ out, const short* __restrict__ out_bf,
    const float* __restrict__ nsum, const float* __restrict__ skip)
{
    int i = blockIdx.x * blockDim.x + threadIdx.x;   // over NN*32 groups of 4 ch
    if (i >= NN * 32) return;
    int n  = i >> 5;
    int c4 = i & 31;
    int h  = c4 >> 4;
    float z = nsum[(size_t)n * 2 + h] + 1e-16f;
    float inv = 1.0f / z;
    short4 ob = ((const short4*)out_bf)[i];
    float4 s  = ((const float4*)skip)[i];
    float4 o;
    o.x = bf2f(ob.x) * inv + s.x;
    o.y = bf2f(ob.y) * inv + s.y;
    o.z = bf2f(ob.z) * inv + s.z;
    o.w = bf2f(ob.w) * inv + s.w;
    ((float4*)out)[i] = o;
}

// ---------------------------------------------------------------------------
extern "C" void kernel_launch(void* const* d_in, const int* in_sizes, int n_in,
                              void* d_out, int out_size, void* d_ws, size_t ws_size,
                              hipStream_t stream) {
    const float* x      = (const float*)d_in[0];
    const float* lastup = (const float*)d_in[1];
    const float* tarr   = (const float*)d_in[2];
    const float* msg    = (const float*)d_in[3];
    const float* time_w = (const float*)d_in[4];
    const float* time_b = (const float*)d_in[5];
    const float* Wq     = (const float*)d_in[6];
    const float* bq     = (const float*)d_in[7];
    const float* Wk     = (const float*)d_in[8];
    const float* bk     = (const float*)d_in[9];
    const float* Wv     = (const float*)d_in[10];
    const float* bv     = (const float*)d_in[11];
    const float* We     = (const float*)d_in[12];
    const float* Wskip  = (const float*)d_in[13];
    const float* bskip  = (const float*)d_in[14];
    const int*   ei     = (const int*)d_in[15];

    // ws layout: q|k|v|skip (fp32) | nsum (fp32) | WeT | WT | xb(=out_bf) (bf16)
    float* ws   = (float*)d_ws;
    float* q    = ws;
    float* k    = q    + (size_t)NN * HC;
    float* v    = k    + (size_t)NN * HC;
    float* skip = v    + (size_t)NN * HC;
    float* nsum = skip + (size_t)NN * HC;
    short* WeT  = (short*)(nsum + (size_t)NN * 2);
    short* WT   = WeT + (size_t)HC * ED;
    short* xb   = WT + (size_t)4 * 128 * 128;   // reused as out_bf after proj
    short* out_bf = xb;
    float* out  = (float*)d_out;

    prep_xb<<<dim3((NN * 32 + 255) / 256), 256, 0, stream>>>(x, xb);
    prep_weights<<<dim3((HC * ED + 4 * 128 * 128 + 255) / 256), 256, 0, stream>>>(
        We, Wq, Wk, Wv, Wskip, WeT, WT);

    proj_mfma<<<dim3((NN + 31) / 32), 256, 0, stream>>>(
        xb, WT, bq, bk, bv, bskip, q, k, v, skip);

    // xb is dead now; reuse as bf16 accumulator
    hipMemsetAsync(out_bf, 0, (size_t)NN * HC * sizeof(short), stream);
    hipMemsetAsync(nsum,   0, (size_t)NN * 2  * sizeof(float), stream);

    edge_kernel<<<dim3(NE / TILE_E), 256, 0, stream>>>(
        ei, tarr, lastup, msg, time_w, time_b, WeT, q, k, v, out_bf, nsum);

    finalize_kernel<<<dim3((NN * 32 + 255) / 256), 256, 0, stream>>>(
        out, out_bf, nsum, skip);
}